// Round 11
// baseline (321.234 us; speedup 1.0000x reference)
//
#include <hip/hip_runtime.h>

#define H 8
#define C 64
#define HC 512
#define NEG 0.2f

typedef __attribute__((ext_vector_type(8))) _Float16 half8v;
typedef __attribute__((ext_vector_type(4))) _Float16 half4v;
typedef __attribute__((ext_vector_type(4))) float f32x4;

__device__ __forceinline__ float leaky(float x) { return x > 0.f ? x : NEG * x; }

#define GLOAD_LDS16(gp, lp) \
  __builtin_amdgcn_global_load_lds((const __attribute__((address_space(1))) unsigned int*)(gp), \
                                   (__attribute__((address_space(3))) unsigned int*)(lp), 16, 0, 0)

// ---------------- CSR build (dst-sorted) ----------------
__global__ void k_degree(const int* __restrict__ ei, int E, int N, int* __restrict__ deg) {
    int e = blockIdx.x * blockDim.x + threadIdx.x;
    int Et = E + N;
    if (e >= Et) return;
    int d = (e < E) ? ei[E + e] : (e - E);
    atomicAdd(&deg[d], 1);
}

__global__ __launch_bounds__(1024) void k_scan(const int* __restrict__ deg, int N, int* __restrict__ row_start) {
    __shared__ int part[1024];
    int t = threadIdx.x;
    int chunk = (N + 1023) >> 10;
    int lo = t * chunk, hi = min(lo + chunk, N);
    int s = 0;
    for (int i = lo; i < hi; ++i) s += deg[i];
    part[t] = s;
    __syncthreads();
    for (int off = 1; off < 1024; off <<= 1) {
        int v = (t >= off) ? part[t - off] : 0;
        __syncthreads();
        part[t] += v;
        __syncthreads();
    }
    int base = (t == 0) ? 0 : part[t - 1];
    for (int i = lo; i < hi; ++i) { row_start[i] = base; base += deg[i]; }
    if (t == 1023) row_start[N] = part[1023];
}

__global__ void k_fill(const int* __restrict__ ei, int E, int N,
                       const int* __restrict__ row_start, int* __restrict__ cursor,
                       int* __restrict__ csr_src, int* __restrict__ csr_eid) {
    int e = blockIdx.x * blockDim.x + threadIdx.x;
    int Et = E + N;
    if (e >= Et) return;
    int d, s;
    if (e < E) { s = ei[e]; d = ei[E + e]; } else { s = e - E; d = s; }
    int pos = atomicAdd(&cursor[d], 1);
    int idx = row_start[d] + pos;
    csr_src[idx] = s;
    csr_eid[idx] = e;
}

// ---------------- conversions ----------------
__global__ void k_tofp16(const float* __restrict__ in, _Float16* __restrict__ out, int n4) {
    int i = blockIdx.x * blockDim.x + threadIdx.x;
    if (i >= n4) return;
    float4 v = reinterpret_cast<const float4*>(in)[i];
    half4v h;
    h[0] = (_Float16)v.x; h[1] = (_Float16)v.y;
    h[2] = (_Float16)v.z; h[3] = (_Float16)v.w;
    reinterpret_cast<half4v*>(out)[i] = h;
}

// W [K][Nc] fp32 -> Wt hi/lo [Nc][K] fp16
__global__ void k_tsplit(const float* __restrict__ W, _Float16* __restrict__ th,
                         _Float16* __restrict__ tl, int K, int Nc) {
    int idx = blockIdx.x * blockDim.x + threadIdx.x;
    if (idx >= K * Nc) return;
    int c = idx / K, k = idx - c * K;
    float v = W[(long)k * Nc + c];
    _Float16 hh = (_Float16)v;
    th[idx] = hh;
    tl[idx] = (_Float16)(v - (float)hh);
}

// ---------------- MFMA GEMM (fp16 2-pass, 2-phase dbuf) + fused attn-dot epilogue ----------------
// hpre written HEAD-MAJOR fp16: Cc[h][Mpad][64]. XCD panel-affinity 1-D grid.
__global__ __launch_bounds__(256) void k_gemm_mfma(const _Float16* __restrict__ A,
                                                   const _Float16* __restrict__ Bh,
                                                   const _Float16* __restrict__ Bl,
                                                   _Float16* __restrict__ Cc, int M, int K, int Pb, int Mpad,
                                                   const float* __restrict__ a_src, const float* __restrict__ a_dst,
                                                   float* __restrict__ e_src, float* __restrict__ e_dst) {
    __shared__ _Float16 lA[8192], lBh[8192], lBl[8192];   // 2 buffers x 4096
    int bid = blockIdx.x;
    int panel = ((bid >> 5) << 3) + (bid & 7);
    int colb  = (bid >> 3) & 3;
    if (panel >= Pb) return;
    int tid = threadIdx.x;
    int w = tid >> 6, lane = tid & 63;
    int wr = w >> 1, wc = w & 1;
    int r0 = panel * 128, c0 = colb * 128;
    f32x4 acc[4][4] = {};
    int frag_off = ((lane >> 4) * 16 + (lane & 15)) * 8;

    int rb0 = tid >> 6, kc0 = (tid >> 4) & 3, r16_0 = tid & 15;
    int rb1 = (256 + tid) >> 6, kc1 = ((256 + tid) >> 4) & 3;
    long gaBase0 = (long)(r0 + rb0 * 16 + r16_0) * K + kc0 * 8;
    long gbBase0 = (long)(c0 + rb0 * 16 + r16_0) * K + kc0 * 8;
    long gaBase1 = (long)(r0 + rb1 * 16 + r16_0) * K + kc1 * 8;
    long gbBase1 = (long)(c0 + rb1 * 16 + r16_0) * K + kc1 * 8;
    int ldst0 = (w * 64) * 8;
    int ldst1 = (256 + w * 64) * 8;

#define STAGE(buf, k0)  do { \
        int off = (buf) * 4096; \
        GLOAD_LDS16(A  + gaBase0 + (k0), lA  + off + ldst0); \
        GLOAD_LDS16(Bh + gbBase0 + (k0), lBh + off + ldst0); \
        GLOAD_LDS16(Bl + gbBase0 + (k0), lBl + off + ldst0); \
        GLOAD_LDS16(A  + gaBase1 + (k0), lA  + off + ldst1); \
        GLOAD_LDS16(Bh + gbBase1 + (k0), lBh + off + ldst1); \
        GLOAD_LDS16(Bl + gbBase1 + (k0), lBl + off + ldst1); \
    } while (0)

    int nk = K >> 5;
    STAGE(0, 0);
    __syncthreads();
    int cur = 0;
    for (int t = 0; t < nk; ++t) {
        if (t + 1 < nk) STAGE(cur ^ 1, (t + 1) * 32);
        int off = cur * 4096;
        half8v fa[4], fbh[4], fbl[4];
        #pragma unroll
        for (int m = 0; m < 4; ++m) {
            int sa = off + (wr * 4 + m) * 512 + frag_off;
            fa[m] = *reinterpret_cast<half8v*>(&lA[sa]);
            int sb = off + (wc * 4 + m) * 512 + frag_off;
            fbh[m] = *reinterpret_cast<half8v*>(&lBh[sb]);
            fbl[m] = *reinterpret_cast<half8v*>(&lBl[sb]);
        }
        #pragma unroll
        for (int m = 0; m < 4; ++m)
            #pragma unroll
            for (int n = 0; n < 4; ++n) {
                acc[m][n] = __builtin_amdgcn_mfma_f32_16x16x32_f16(fa[m], fbh[n], acc[m][n], 0, 0, 0);
                acc[m][n] = __builtin_amdgcn_mfma_f32_16x16x32_f16(fa[m], fbl[n], acc[m][n], 0, 0, 0);
            }
        __syncthreads();
        cur ^= 1;
    }
#undef STAGE

    int head = colb * 2 + wc;
    long hbase = (long)head * Mpad * 64;
    #pragma unroll
    for (int m = 0; m < 4; ++m)
        #pragma unroll
        for (int j = 0; j < 4; ++j) {
            int gr = r0 + wr * 64 + m * 16 + (lane >> 4) * 4 + j;
            if (gr < M) {
                #pragma unroll
                for (int n = 0; n < 4; ++n)
                    Cc[hbase + (long)gr * 64 + n * 16 + (lane & 15)] = (_Float16)acc[m][n][j];
            }
        }
    float asv[4], adv[4];
    #pragma unroll
    for (int nn = 0; nn < 4; ++nn) {
        asv[nn] = a_src[head * 64 + nn * 16 + (lane & 15)];
        adv[nn] = a_dst[head * 64 + nn * 16 + (lane & 15)];
    }
    #pragma unroll
    for (int m = 0; m < 4; ++m)
        #pragma unroll
        for (int j = 0; j < 4; ++j) {
            int gr = r0 + wr * 64 + m * 16 + (lane >> 4) * 4 + j;
            float es = 0.f, ed = 0.f;
            #pragma unroll
            for (int nn = 0; nn < 4; ++nn) {
                es = fmaf(acc[m][nn][j], asv[nn], es);
                ed = fmaf(acc[m][nn][j], adv[nn], ed);
            }
            #pragma unroll
            for (int o = 1; o < 16; o <<= 1) {
                es += __shfl_xor(es, o);
                ed += __shfl_xor(ed, o);
            }
            if ((lane & 15) == 0 && gr < M) {
                e_src[gr * 8 + head] = es;
                e_dst[gr * 8 + head] = ed;
            }
        }
}

// ---------------- k_edge: softmax denom + alpha, wave = 2 nodes x 4 edge-slots x 8 heads ----------------
// lane = g*32 + eg*8 + h. 10000 waves -> full TLP. p recomputed in pass 2 (L2-hot).
__global__ __launch_bounds__(512) void k_edge(const float* __restrict__ e_src,
                                              const float* __restrict__ e_dst,
                                              const int* __restrict__ row_start,
                                              const int* __restrict__ csr_src,
                                              const int* __restrict__ csr_eid,
                                              float* __restrict__ inv_buf,
                                              float* __restrict__ alpha,
                                              int N) {
    int wid = threadIdx.x >> 6, lane = threadIdx.x & 63;
    int g = lane >> 5;                 // node sub-index 0..1
    int eg = (lane >> 3) & 3;          // edge slot 0..3
    int h = lane & 7;                  // head
    int n = blockIdx.x * 16 + wid * 2 + g;
    bool valid = (n < N);
    int nc = valid ? n : (N - 1);
    int row = row_start[nc];
    int deg = row_start[nc + 1] - row;
    float ed = e_dst[nc * 8 + h];
    int it = (deg + 3) >> 2;
    int itmax = max(it, __shfl_xor(it, 32));
    float psum = 0.f;
    for (int c = 0; c < itmax; ++c) {
        int e0 = c * 4 + eg;
        int idx = row + min(e0, deg - 1);
        int s = csr_src[idx];          // broadcast within 8-lane head group
        float p = (e0 < deg) ? __expf(leaky(e_src[s * 8 + h] + ed)) : 0.f;
        psum += p;
    }
    psum += __shfl_xor(psum, 8);
    psum += __shfl_xor(psum, 16);
    float inv = 1.0f / psum;
    if (valid && eg == 0) inv_buf[n * 8 + h] = inv;
    // pass 2: alpha (recompute p; csr/e_src L2-hot)
    for (int c = 0; c < itmax; ++c) {
        int e0 = c * 4 + eg;
        int idx = row + min(e0, deg - 1);
        int s = csr_src[idx];
        int eid = csr_eid[idx];
        float p = (e0 < deg) ? __expf(leaky(e_src[s * 8 + h] + ed)) : 0.f;
        if (valid && e0 < deg)
            alpha[(long)eid * 8 + h] = p * inv;   // 32B contiguous per 8-lane group
    }
}

// ---------------- k_gather: XCD-affine aggregation, wave = 2 nodes x 4 edge-slots ----------------
// head = blockIdx.x & 7 (XCD round-robin keeps head slice L2-resident).
// lane = g*32 + eg*8 + cg. 4 independent gather chains per node per iter.
__global__ __launch_bounds__(512) void k_gather(const half8v* __restrict__ hp8,
                                                const float* __restrict__ e_src,
                                                const float* __restrict__ e_dst,
                                                const int* __restrict__ row_start,
                                                const int* __restrict__ csr_src,
                                                const float* __restrict__ inv_buf,
                                                const float* __restrict__ bias,
                                                _Float16* __restrict__ h1,
                                                _Float16* __restrict__ accq,
                                                int N, int Mpad, int concat) {
    int wid = threadIdx.x >> 6, lane = threadIdx.x & 63;
    int bid = blockIdx.x;
    int h = bid & 7;
    int g = lane >> 5;                 // node sub-index 0..1
    int eg = (lane >> 3) & 3;          // edge slot 0..3
    int cg = lane & 7;                 // 16B chan-oct
    int n = (bid >> 3) * 16 + wid * 2 + g;
    bool valid = (n < N);
    int nc = valid ? n : (N - 1);
    long hoff = (long)h * Mpad * 8;    // half8 units
    int row = row_start[nc];
    int deg = row_start[nc + 1] - row;
    float ed = e_dst[nc * 8 + h];
    int it = (deg + 3) >> 2;
    int itmax = max(it, __shfl_xor(it, 32));
    float acc[8] = {};
    for (int c = 0; c < itmax; ++c) {
        int e0 = c * 4 + eg;
        int idx = row + min(e0, deg - 1);
        int s = csr_src[idx];          // broadcast within 8-lane group
        float es = e_src[s * 8 + h];
        float p = (e0 < deg) ? __expf(leaky(es + ed)) : 0.f;
        half8v hv = hp8[hoff + (long)s * 8 + cg];
        #pragma unroll
        for (int k = 0; k < 8; ++k)
            acc[k] = fmaf((float)hv[k], p, acc[k]);
    }
    // reduce across 4 edge slots (xor 8, 16 — stays within node half & chan lane)
    #pragma unroll
    for (int o = 8; o <= 16; o <<= 1)
        #pragma unroll
        for (int k = 0; k < 8; ++k)
            acc[k] += __shfl_xor(acc[k], o);
    if (!valid) return;
    float inv = inv_buf[n * 8 + h];
    if (eg == 0) {                     // 8 lanes per node hold the 64 channels
        if (concat) {
            half8v hh;
            #pragma unroll
            for (int k = 0; k < 8; ++k) {
                float v = fmaf(acc[k], inv, bias[h * 64 + cg * 8 + k]);
                v = v > 0.f ? v : 0.f;
                hh[k] = (_Float16)v;
            }
            reinterpret_cast<half8v*>(h1)[(long)n * 64 + h * 8 + cg] = hh;   // node-major
        } else {
            half8v hv2;
            #pragma unroll
            for (int k = 0; k < 8; ++k) hv2[k] = (_Float16)(acc[k] * inv);
            reinterpret_cast<half8v*>(accq)[hoff + (long)n * 8 + cg] = hv2;  // head-major
        }
    }
}

// ---------------- mean over heads + bias (layer 2 finish) ----------------
__global__ void k_mean(const _Float16* __restrict__ accq, const float* __restrict__ bias,
                       float* __restrict__ out, int N, int Mpad) {
    int i = blockIdx.x * blockDim.x + threadIdx.x;   // over N*8 chan-octs
    if (i >= N * 8) return;
    int n = i >> 3, cg = i & 7;
    float s[8] = {};
    #pragma unroll
    for (int h = 0; h < 8; ++h) {
        half8v v = reinterpret_cast<const half8v*>(accq)[(long)h * Mpad * 8 + (long)n * 8 + cg];
        #pragma unroll
        for (int k = 0; k < 8; ++k) s[k] += (float)v[k];
    }
    float4 r0, r1;
    r0.x = s[0] * 0.125f + bias[cg * 8 + 0];
    r0.y = s[1] * 0.125f + bias[cg * 8 + 1];
    r0.z = s[2] * 0.125f + bias[cg * 8 + 2];
    r0.w = s[3] * 0.125f + bias[cg * 8 + 3];
    r1.x = s[4] * 0.125f + bias[cg * 8 + 4];
    r1.y = s[5] * 0.125f + bias[cg * 8 + 5];
    r1.z = s[6] * 0.125f + bias[cg * 8 + 6];
    r1.w = s[7] * 0.125f + bias[cg * 8 + 7];
    float4* o4 = reinterpret_cast<float4*>(out + (long)n * 64 + cg * 8);
    o4[0] = r0;
    o4[1] = r1;
}

extern "C" void kernel_launch(void* const* d_in, const int* in_sizes, int n_in,
                              void* d_out, int out_size, void* d_ws, size_t ws_size,
                              hipStream_t stream) {
    const float* x   = (const float*)d_in[0];
    const int*   ei  = (const int*)d_in[1];
    const float* W1  = (const float*)d_in[2];
    const float* as1 = (const float*)d_in[3];
    const float* ad1 = (const float*)d_in[4];
    const float* b1  = (const float*)d_in[5];
    const float* W2  = (const float*)d_in[6];
    const float* as2 = (const float*)d_in[7];
    const float* ad2 = (const float*)d_in[8];
    const float* b2  = (const float*)d_in[9];

    int N  = in_sizes[0] / 256;
    int E  = in_sizes[1] / 2;
    int Et = E + N;
    int K1 = 256;
    int Mb   = (N + 127) / 128;
    int Mpad = Mb * 128;

    float* out    = (float*)d_out;
    float* h2_out = out;
    float* alpha1 = out + (size_t)N * 64;
    float* alpha2 = alpha1 + (size_t)Et * H;

    _Float16* hpre = (_Float16*)d_ws;                      // [8][Mpad][64] head-major
    _Float16* h1   = hpre + (size_t)Mpad * HC;             // [Mpad][512] node-major
    _Float16* accq = h1 + (size_t)Mpad * HC;               // [8][Mpad][64] head-major
    _Float16* xh   = accq + (size_t)Mpad * HC;             // [Mpad][256]
    _Float16* W1th = xh + (size_t)Mpad * K1;               // [512][256]
    _Float16* W1tl = W1th + (size_t)HC * K1;
    _Float16* W2th = W1tl + (size_t)HC * K1;               // [512][512]
    _Float16* W2tl = W2th + (size_t)HC * HC;
    float* eS     = (float*)(W2tl + (size_t)HC * HC);      // [N][8]
    float* eD     = eS + (size_t)N * H;
    float* invb   = eD + (size_t)N * H;                    // [N][8]
    int*   deg    = (int*)(invb + (size_t)N * H);
    int*   cursor = deg + N;
    int*   row_st = cursor + N;
    int*   csr_src= row_st + N + 1;                        // Et
    int*   csr_eid= csr_src + Et;                          // Et

    hipMemsetAsync(deg, 0, (size_t)2 * N * sizeof(int), stream);
    int tb = 256;
    k_degree<<<(Et + tb - 1) / tb, tb, 0, stream>>>(ei, E, N, deg);
    k_scan<<<1, 1024, 0, stream>>>(deg, N, row_st);
    k_fill<<<(Et + tb - 1) / tb, tb, 0, stream>>>(ei, E, N, row_st, cursor, csr_src, csr_eid);

    int n4 = N * K1 / 4;
    k_tofp16<<<(n4 + tb - 1) / tb, tb, 0, stream>>>(x, xh, n4);
    k_tsplit<<<(K1 * HC + tb - 1) / tb, tb, 0, stream>>>(W1, W1th, W1tl, K1, HC);
    k_tsplit<<<(HC * HC + tb - 1) / tb, tb, 0, stream>>>(W2, W2th, W2tl, HC, HC);

    int Pb8 = ((Mb + 7) / 8) * 8;
    int ggemm = Pb8 * 4;
    int gedge = (N + 15) / 16;
    int ggath = ((N + 15) / 16) * 8;   // low 3 bits = head (XCD affinity)
    // layer 1
    k_gemm_mfma<<<ggemm, 256, 0, stream>>>(xh, W1th, W1tl, hpre, N, K1, Mb, Mpad, as1, ad1, eS, eD);
    k_edge<<<gedge, 512, 0, stream>>>(eS, eD, row_st, csr_src, csr_eid, invb, alpha1, N);
    k_gather<<<ggath, 512, 0, stream>>>((const half8v*)hpre, eS, eD, row_st, csr_src, invb,
                                        b1, h1, nullptr, N, Mpad, 1);
    // layer 2
    k_gemm_mfma<<<ggemm, 256, 0, stream>>>(h1, W2th, W2tl, hpre, N, HC, Mb, Mpad, as2, ad2, eS, eD);
    k_edge<<<gedge, 512, 0, stream>>>(eS, eD, row_st, csr_src, csr_eid, invb, alpha2, N);
    k_gather<<<ggath, 512, 0, stream>>>((const half8v*)hpre, eS, eD, row_st, csr_src, invb,
                                        b2, nullptr, accq, N, Mpad, 0);
    k_mean<<<(N * 8 + tb - 1) / tb, tb, 0, stream>>>(accq, b2, h2_out, N, Mpad);
}

// Round 12
// 286.170 us; speedup vs baseline: 1.1225x; 1.1225x over previous
//
#include <hip/hip_runtime.h>

#define H 8
#define C 64
#define HC 512
#define NEG 0.2f

typedef __attribute__((ext_vector_type(8))) _Float16 half8v;
typedef __attribute__((ext_vector_type(4))) _Float16 half4v;
typedef __attribute__((ext_vector_type(4))) float f32x4;

__device__ __forceinline__ float leaky(float x) { return x > 0.f ? x : NEG * x; }

#define GLOAD_LDS16(gp, lp) \
  __builtin_amdgcn_global_load_lds((const __attribute__((address_space(1))) unsigned int*)(gp), \
                                   (__attribute__((address_space(3))) unsigned int*)(lp), 16, 0, 0)

// ---------------- CSR build (dst-sorted) ----------------
__global__ void k_degree(const int* __restrict__ ei, int E, int N, int* __restrict__ deg) {
    int e = blockIdx.x * blockDim.x + threadIdx.x;
    int Et = E + N;
    if (e >= Et) return;
    int d = (e < E) ? ei[E + e] : (e - E);
    atomicAdd(&deg[d], 1);
}

__global__ __launch_bounds__(1024) void k_scan(const int* __restrict__ deg, int N, int* __restrict__ row_start) {
    __shared__ int part[1024];
    int t = threadIdx.x;
    int chunk = (N + 1023) >> 10;
    int lo = t * chunk, hi = min(lo + chunk, N);
    int s = 0;
    for (int i = lo; i < hi; ++i) s += deg[i];
    part[t] = s;
    __syncthreads();
    for (int off = 1; off < 1024; off <<= 1) {
        int v = (t >= off) ? part[t - off] : 0;
        __syncthreads();
        part[t] += v;
        __syncthreads();
    }
    int base = (t == 0) ? 0 : part[t - 1];
    for (int i = lo; i < hi; ++i) { row_start[i] = base; base += deg[i]; }
    if (t == 1023) row_start[N] = part[1023];
}

__global__ void k_fill(const int* __restrict__ ei, int E, int N,
                       const int* __restrict__ row_start, int* __restrict__ cursor,
                       int* __restrict__ csr_src, int* __restrict__ csr_eid) {
    int e = blockIdx.x * blockDim.x + threadIdx.x;
    int Et = E + N;
    if (e >= Et) return;
    int d, s;
    if (e < E) { s = ei[e]; d = ei[E + e]; } else { s = e - E; d = s; }
    int pos = atomicAdd(&cursor[d], 1);
    int idx = row_start[d] + pos;
    csr_src[idx] = s;
    csr_eid[idx] = e;
}

// ---------------- conversions ----------------
__global__ void k_tofp16(const float* __restrict__ in, _Float16* __restrict__ out, int n4) {
    int i = blockIdx.x * blockDim.x + threadIdx.x;
    if (i >= n4) return;
    float4 v = reinterpret_cast<const float4*>(in)[i];
    half4v h;
    h[0] = (_Float16)v.x; h[1] = (_Float16)v.y;
    h[2] = (_Float16)v.z; h[3] = (_Float16)v.w;
    reinterpret_cast<half4v*>(out)[i] = h;
}

// W [K][Nc] fp32 -> Wt hi/lo [Nc][K] fp16
__global__ void k_tsplit(const float* __restrict__ W, _Float16* __restrict__ th,
                         _Float16* __restrict__ tl, int K, int Nc) {
    int idx = blockIdx.x * blockDim.x + threadIdx.x;
    if (idx >= K * Nc) return;
    int c = idx / K, k = idx - c * K;
    float v = W[(long)k * Nc + c];
    _Float16 hh = (_Float16)v;
    th[idx] = hh;
    tl[idx] = (_Float16)(v - (float)hh);
}

// ---------------- MFMA GEMM (fp16 2-pass, 2-phase dbuf) + fused attn-dot epilogue ----------------
// hpre written HEAD-MAJOR fp16: Cc[h][Mpad][64]. XCD panel-affinity 1-D grid.
__global__ __launch_bounds__(256) void k_gemm_mfma(const _Float16* __restrict__ A,
                                                   const _Float16* __restrict__ Bh,
                                                   const _Float16* __restrict__ Bl,
                                                   _Float16* __restrict__ Cc, int M, int K, int Pb, int Mpad,
                                                   const float* __restrict__ a_src, const float* __restrict__ a_dst,
                                                   float* __restrict__ e_src, float* __restrict__ e_dst) {
    __shared__ _Float16 lA[8192], lBh[8192], lBl[8192];   // 2 buffers x 4096
    int bid = blockIdx.x;
    int panel = ((bid >> 5) << 3) + (bid & 7);
    int colb  = (bid >> 3) & 3;
    if (panel >= Pb) return;
    int tid = threadIdx.x;
    int w = tid >> 6, lane = tid & 63;
    int wr = w >> 1, wc = w & 1;
    int r0 = panel * 128, c0 = colb * 128;
    f32x4 acc[4][4] = {};
    int frag_off = ((lane >> 4) * 16 + (lane & 15)) * 8;

    int rb0 = tid >> 6, kc0 = (tid >> 4) & 3, r16_0 = tid & 15;
    int rb1 = (256 + tid) >> 6, kc1 = ((256 + tid) >> 4) & 3;
    long gaBase0 = (long)(r0 + rb0 * 16 + r16_0) * K + kc0 * 8;
    long gbBase0 = (long)(c0 + rb0 * 16 + r16_0) * K + kc0 * 8;
    long gaBase1 = (long)(r0 + rb1 * 16 + r16_0) * K + kc1 * 8;
    long gbBase1 = (long)(c0 + rb1 * 16 + r16_0) * K + kc1 * 8;
    int ldst0 = (w * 64) * 8;
    int ldst1 = (256 + w * 64) * 8;

#define STAGE(buf, k0)  do { \
        int off = (buf) * 4096; \
        GLOAD_LDS16(A  + gaBase0 + (k0), lA  + off + ldst0); \
        GLOAD_LDS16(Bh + gbBase0 + (k0), lBh + off + ldst0); \
        GLOAD_LDS16(Bl + gbBase0 + (k0), lBl + off + ldst0); \
        GLOAD_LDS16(A  + gaBase1 + (k0), lA  + off + ldst1); \
        GLOAD_LDS16(Bh + gbBase1 + (k0), lBh + off + ldst1); \
        GLOAD_LDS16(Bl + gbBase1 + (k0), lBl + off + ldst1); \
    } while (0)

    int nk = K >> 5;
    STAGE(0, 0);
    __syncthreads();
    int cur = 0;
    for (int t = 0; t < nk; ++t) {
        if (t + 1 < nk) STAGE(cur ^ 1, (t + 1) * 32);
        int off = cur * 4096;
        half8v fa[4], fbh[4], fbl[4];
        #pragma unroll
        for (int m = 0; m < 4; ++m) {
            int sa = off + (wr * 4 + m) * 512 + frag_off;
            fa[m] = *reinterpret_cast<half8v*>(&lA[sa]);
            int sb = off + (wc * 4 + m) * 512 + frag_off;
            fbh[m] = *reinterpret_cast<half8v*>(&lBh[sb]);
            fbl[m] = *reinterpret_cast<half8v*>(&lBl[sb]);
        }
        #pragma unroll
        for (int m = 0; m < 4; ++m)
            #pragma unroll
            for (int n = 0; n < 4; ++n) {
                acc[m][n] = __builtin_amdgcn_mfma_f32_16x16x32_f16(fa[m], fbh[n], acc[m][n], 0, 0, 0);
                acc[m][n] = __builtin_amdgcn_mfma_f32_16x16x32_f16(fa[m], fbl[n], acc[m][n], 0, 0, 0);
            }
        __syncthreads();
        cur ^= 1;
    }
#undef STAGE

    int head = colb * 2 + wc;
    long hbase = (long)head * Mpad * 64;
    #pragma unroll
    for (int m = 0; m < 4; ++m)
        #pragma unroll
        for (int j = 0; j < 4; ++j) {
            int gr = r0 + wr * 64 + m * 16 + (lane >> 4) * 4 + j;
            if (gr < M) {
                #pragma unroll
                for (int n = 0; n < 4; ++n)
                    Cc[hbase + (long)gr * 64 + n * 16 + (lane & 15)] = (_Float16)acc[m][n][j];
            }
        }
    float asv[4], adv[4];
    #pragma unroll
    for (int nn = 0; nn < 4; ++nn) {
        asv[nn] = a_src[head * 64 + nn * 16 + (lane & 15)];
        adv[nn] = a_dst[head * 64 + nn * 16 + (lane & 15)];
    }
    #pragma unroll
    for (int m = 0; m < 4; ++m)
        #pragma unroll
        for (int j = 0; j < 4; ++j) {
            int gr = r0 + wr * 64 + m * 16 + (lane >> 4) * 4 + j;
            float es = 0.f, ed = 0.f;
            #pragma unroll
            for (int nn = 0; nn < 4; ++nn) {
                es = fmaf(acc[m][nn][j], asv[nn], es);
                ed = fmaf(acc[m][nn][j], adv[nn], ed);
            }
            #pragma unroll
            for (int o = 1; o < 16; o <<= 1) {
                es += __shfl_xor(es, o);
                ed += __shfl_xor(ed, o);
            }
            if ((lane & 15) == 0 && gr < M) {
                e_src[gr * 8 + head] = es;
                e_dst[gr * 8 + head] = ed;
            }
        }
}

// ---------------- k_edge: softmax denom + alpha (scattered + CSR-ordered) ----------------
// wave = 2 nodes x 4 edge-slots x 8 heads; lane = g*32 + eg*8 + h.
// Writes alpha[eid][h] (output) AND alp_csr[idx][h] (sequential, feeds k_gather).
__global__ __launch_bounds__(512) void k_edge(const float* __restrict__ e_src,
                                              const float* __restrict__ e_dst,
                                              const int* __restrict__ row_start,
                                              const int* __restrict__ csr_src,
                                              const int* __restrict__ csr_eid,
                                              float* __restrict__ alpha,
                                              float* __restrict__ alp_csr,
                                              int N) {
    int wid = threadIdx.x >> 6, lane = threadIdx.x & 63;
    int g = lane >> 5;
    int eg = (lane >> 3) & 3;
    int h = lane & 7;
    int n = blockIdx.x * 16 + wid * 2 + g;
    bool valid = (n < N);
    int nc = valid ? n : (N - 1);
    int row = row_start[nc];
    int deg = row_start[nc + 1] - row;
    float ed = e_dst[nc * 8 + h];
    int it = (deg + 3) >> 2;
    int itmax = max(it, __shfl_xor(it, 32));
    float psum = 0.f;
    for (int c = 0; c < itmax; ++c) {
        int e0 = c * 4 + eg;
        int idx = row + min(e0, deg - 1);
        int s = csr_src[idx];
        float p = (e0 < deg) ? __expf(leaky(e_src[s * 8 + h] + ed)) : 0.f;
        psum += p;
    }
    psum += __shfl_xor(psum, 8);
    psum += __shfl_xor(psum, 16);
    float inv = 1.0f / psum;
    // pass 2: alpha (recompute p; csr/e_src L2-hot)
    for (int c = 0; c < itmax; ++c) {
        int e0 = c * 4 + eg;
        int idx = row + min(e0, deg - 1);
        int s = csr_src[idx];
        int eid = csr_eid[idx];
        float p = (e0 < deg) ? __expf(leaky(e_src[s * 8 + h] + ed)) : 0.f;
        if (valid && e0 < deg) {
            float a = p * inv;
            alpha[(long)eid * 8 + h] = a;          // scattered 32B per group
            alp_csr[(long)idx * 8 + h] = a;        // sequential 32B per group
        }
    }
}

// ---------------- k_gather: XCD-affine aggregation via precomputed CSR alpha ----------------
// head = blockIdx.x & 7 (XCD round-robin keeps 2.57MB head slice L2-resident).
// lane = g*32 + eg*8 + cg. Loop chain is 1-level: prefetched (s,a) -> hv -> fma.
__global__ __launch_bounds__(512) void k_gather(const half8v* __restrict__ hp8,
                                                const int* __restrict__ row_start,
                                                const int* __restrict__ csr_src,
                                                const float* __restrict__ alp_csr,
                                                const float* __restrict__ bias,
                                                _Float16* __restrict__ h1,
                                                _Float16* __restrict__ accq,
                                                int N, int Mpad, int concat) {
    int wid = threadIdx.x >> 6, lane = threadIdx.x & 63;
    int bid = blockIdx.x;
    int h = bid & 7;
    int g = lane >> 5;
    int eg = (lane >> 3) & 3;
    int cg = lane & 7;
    int n = (bid >> 3) * 16 + wid * 2 + g;
    bool valid = (n < N);
    int nc = valid ? n : (N - 1);
    long hoff = (long)h * Mpad * 8;
    int row = row_start[nc];
    int deg = row_start[nc + 1] - row;
    int it = (deg + 3) >> 2;
    int itmax = max(it, __shfl_xor(it, 32));
    float acc[8] = {};
    // prefetch iter 0
    int idx0 = row + min(eg, deg - 1);
    int s_pf = csr_src[idx0];
    float a_pf = alp_csr[(long)idx0 * 8 + h];
    for (int c = 0; c < itmax; ++c) {
        int s_cur = s_pf;
        float a_cur = a_pf;
        int e0 = c * 4 + eg;
        if (c + 1 < itmax) {                       // prefetch next (index-independent)
            int idxn = row + min(e0 + 4, deg - 1);
            s_pf = csr_src[idxn];
            a_pf = alp_csr[(long)idxn * 8 + h];
        }
        float a = (e0 < deg) ? a_cur : 0.f;
        half8v hv = hp8[hoff + (long)s_cur * 8 + cg];
        #pragma unroll
        for (int k = 0; k < 8; ++k)
            acc[k] = fmaf((float)hv[k], a, acc[k]);
    }
    #pragma unroll
    for (int o = 8; o <= 16; o <<= 1)
        #pragma unroll
        for (int k = 0; k < 8; ++k)
            acc[k] += __shfl_xor(acc[k], o);
    if (!valid) return;
    if (eg == 0) {                     // 8 lanes per node hold the 64 channels
        if (concat) {
            half8v hh;
            #pragma unroll
            for (int k = 0; k < 8; ++k) {
                float v = acc[k] + bias[h * 64 + cg * 8 + k];
                v = v > 0.f ? v : 0.f;
                hh[k] = (_Float16)v;
            }
            reinterpret_cast<half8v*>(h1)[(long)n * 64 + h * 8 + cg] = hh;   // node-major
        } else {
            half8v hv2;
            #pragma unroll
            for (int k = 0; k < 8; ++k) hv2[k] = (_Float16)acc[k];
            reinterpret_cast<half8v*>(accq)[hoff + (long)n * 8 + cg] = hv2;  // head-major
        }
    }
}

// ---------------- mean over heads + bias (layer 2 finish) ----------------
__global__ void k_mean(const _Float16* __restrict__ accq, const float* __restrict__ bias,
                       float* __restrict__ out, int N, int Mpad) {
    int i = blockIdx.x * blockDim.x + threadIdx.x;   // over N*8 chan-octs
    if (i >= N * 8) return;
    int n = i >> 3, cg = i & 7;
    float s[8] = {};
    #pragma unroll
    for (int h = 0; h < 8; ++h) {
        half8v v = reinterpret_cast<const half8v*>(accq)[(long)h * Mpad * 8 + (long)n * 8 + cg];
        #pragma unroll
        for (int k = 0; k < 8; ++k) s[k] += (float)v[k];
    }
    float4 r0, r1;
    r0.x = s[0] * 0.125f + bias[cg * 8 + 0];
    r0.y = s[1] * 0.125f + bias[cg * 8 + 1];
    r0.z = s[2] * 0.125f + bias[cg * 8 + 2];
    r0.w = s[3] * 0.125f + bias[cg * 8 + 3];
    r1.x = s[4] * 0.125f + bias[cg * 8 + 4];
    r1.y = s[5] * 0.125f + bias[cg * 8 + 5];
    r1.z = s[6] * 0.125f + bias[cg * 8 + 6];
    r1.w = s[7] * 0.125f + bias[cg * 8 + 7];
    float4* o4 = reinterpret_cast<float4*>(out + (long)n * 64 + cg * 8);
    o4[0] = r0;
    o4[1] = r1;
}

extern "C" void kernel_launch(void* const* d_in, const int* in_sizes, int n_in,
                              void* d_out, int out_size, void* d_ws, size_t ws_size,
                              hipStream_t stream) {
    const float* x   = (const float*)d_in[0];
    const int*   ei  = (const int*)d_in[1];
    const float* W1  = (const float*)d_in[2];
    const float* as1 = (const float*)d_in[3];
    const float* ad1 = (const float*)d_in[4];
    const float* b1  = (const float*)d_in[5];
    const float* W2  = (const float*)d_in[6];
    const float* as2 = (const float*)d_in[7];
    const float* ad2 = (const float*)d_in[8];
    const float* b2  = (const float*)d_in[9];

    int N  = in_sizes[0] / 256;
    int E  = in_sizes[1] / 2;
    int Et = E + N;
    int K1 = 256;
    int Mb   = (N + 127) / 128;
    int Mpad = Mb * 128;

    float* out    = (float*)d_out;
    float* h2_out = out;
    float* alpha1 = out + (size_t)N * 64;
    float* alpha2 = alpha1 + (size_t)Et * H;

    _Float16* hpre = (_Float16*)d_ws;                      // [8][Mpad][64] head-major
    _Float16* h1   = hpre + (size_t)Mpad * HC;             // [Mpad][512] node-major
    _Float16* accq = h1 + (size_t)Mpad * HC;               // [8][Mpad][64] head-major
    _Float16* xh   = accq + (size_t)Mpad * HC;             // [Mpad][256]
    _Float16* W1th = xh + (size_t)Mpad * K1;               // [512][256]
    _Float16* W1tl = W1th + (size_t)HC * K1;
    _Float16* W2th = W1tl + (size_t)HC * K1;               // [512][512]
    _Float16* W2tl = W2th + (size_t)HC * HC;
    float* eS     = (float*)(W2tl + (size_t)HC * HC);      // [N][8]
    float* eD     = eS + (size_t)N * H;
    float* alpcsr = eD + (size_t)N * H;                    // [Et][8]
    int*   deg    = (int*)(alpcsr + (size_t)Et * H);
    int*   cursor = deg + N;
    int*   row_st = cursor + N;
    int*   csr_src= row_st + N + 1;                        // Et
    int*   csr_eid= csr_src + Et;                          // Et

    hipMemsetAsync(deg, 0, (size_t)2 * N * sizeof(int), stream);
    int tb = 256;
    k_degree<<<(Et + tb - 1) / tb, tb, 0, stream>>>(ei, E, N, deg);
    k_scan<<<1, 1024, 0, stream>>>(deg, N, row_st);
    k_fill<<<(Et + tb - 1) / tb, tb, 0, stream>>>(ei, E, N, row_st, cursor, csr_src, csr_eid);

    int n4 = N * K1 / 4;
    k_tofp16<<<(n4 + tb - 1) / tb, tb, 0, stream>>>(x, xh, n4);
    k_tsplit<<<(K1 * HC + tb - 1) / tb, tb, 0, stream>>>(W1, W1th, W1tl, K1, HC);
    k_tsplit<<<(HC * HC + tb - 1) / tb, tb, 0, stream>>>(W2, W2th, W2tl, HC, HC);

    int Pb8 = ((Mb + 7) / 8) * 8;
    int ggemm = Pb8 * 4;
    int gedge = (N + 15) / 16;
    int ggath = ((N + 15) / 16) * 8;   // low 3 bits = head (XCD affinity)
    // layer 1
    k_gemm_mfma<<<ggemm, 256, 0, stream>>>(xh, W1th, W1tl, hpre, N, K1, Mb, Mpad, as1, ad1, eS, eD);
    k_edge<<<gedge, 512, 0, stream>>>(eS, eD, row_st, csr_src, csr_eid, alpha1, alpcsr, N);
    k_gather<<<ggath, 512, 0, stream>>>((const half8v*)hpre, row_st, csr_src, alpcsr,
                                        b1, h1, nullptr, N, Mpad, 1);
    // layer 2
    k_gemm_mfma<<<ggemm, 256, 0, stream>>>(h1, W2th, W2tl, hpre, N, HC, Mb, Mpad, as2, ad2, eS, eD);
    k_edge<<<gedge, 512, 0, stream>>>(eS, eD, row_st, csr_src, csr_eid, alpha2, alpcsr, N);
    k_gather<<<ggath, 512, 0, stream>>>((const half8v*)hpre, row_st, csr_src, alpcsr,
                                        b2, nullptr, accq, N, Mpad, 0);
    k_mean<<<(N * 8 + tb - 1) / tb, tb, 0, stream>>>(accq, b2, h2_out, N, Mpad);
}

// Round 13
// 280.506 us; speedup vs baseline: 1.1452x; 1.0202x over previous
//
#include <hip/hip_runtime.h>

#define H 8
#define C 64
#define HC 512
#define NEG 0.2f

typedef __attribute__((ext_vector_type(8))) _Float16 half8v;
typedef __attribute__((ext_vector_type(4))) _Float16 half4v;
typedef __attribute__((ext_vector_type(4))) float f32x4;

__device__ __forceinline__ float leaky(float x) { return x > 0.f ? x : NEG * x; }

#define GLOAD_LDS16(gp, lp) \
  __builtin_amdgcn_global_load_lds((const __attribute__((address_space(1))) unsigned int*)(gp), \
                                   (__attribute__((address_space(3))) unsigned int*)(lp), 16, 0, 0)

// ---------------- CSR build (dst-sorted) ----------------
__global__ void k_degree(const int* __restrict__ ei, int E, int N, int* __restrict__ deg) {
    int e = blockIdx.x * blockDim.x + threadIdx.x;
    int Et = E + N;
    if (e >= Et) return;
    int d = (e < E) ? ei[E + e] : (e - E);
    atomicAdd(&deg[d], 1);
}

__global__ __launch_bounds__(1024) void k_scan(const int* __restrict__ deg, int N, int* __restrict__ row_start) {
    __shared__ int part[1024];
    int t = threadIdx.x;
    int chunk = (N + 1023) >> 10;
    int lo = t * chunk, hi = min(lo + chunk, N);
    int s = 0;
    for (int i = lo; i < hi; ++i) s += deg[i];
    part[t] = s;
    __syncthreads();
    for (int off = 1; off < 1024; off <<= 1) {
        int v = (t >= off) ? part[t - off] : 0;
        __syncthreads();
        part[t] += v;
        __syncthreads();
    }
    int base = (t == 0) ? 0 : part[t - 1];
    for (int i = lo; i < hi; ++i) { row_start[i] = base; base += deg[i]; }
    if (t == 1023) row_start[N] = part[1023];
}

__global__ void k_fill(const int* __restrict__ ei, int E, int N,
                       const int* __restrict__ row_start, int* __restrict__ cursor,
                       int* __restrict__ csr_src, int* __restrict__ csr_eid,
                       int* __restrict__ csr_dst) {
    int e = blockIdx.x * blockDim.x + threadIdx.x;
    int Et = E + N;
    if (e >= Et) return;
    int d, s;
    if (e < E) { s = ei[e]; d = ei[E + e]; } else { s = e - E; d = s; }
    int pos = atomicAdd(&cursor[d], 1);
    int idx = row_start[d] + pos;
    csr_src[idx] = s;
    csr_eid[idx] = e;
    csr_dst[idx] = d;
}

// ---------------- conversions ----------------
__global__ void k_tofp16(const float* __restrict__ in, _Float16* __restrict__ out, int n4) {
    int i = blockIdx.x * blockDim.x + threadIdx.x;
    if (i >= n4) return;
    float4 v = reinterpret_cast<const float4*>(in)[i];
    half4v h;
    h[0] = (_Float16)v.x; h[1] = (_Float16)v.y;
    h[2] = (_Float16)v.z; h[3] = (_Float16)v.w;
    reinterpret_cast<half4v*>(out)[i] = h;
}

// W [K][Nc] fp32 -> Wt hi/lo [Nc][K] fp16
__global__ void k_tsplit(const float* __restrict__ W, _Float16* __restrict__ th,
                         _Float16* __restrict__ tl, int K, int Nc) {
    int idx = blockIdx.x * blockDim.x + threadIdx.x;
    if (idx >= K * Nc) return;
    int c = idx / K, k = idx - c * K;
    float v = W[(long)k * Nc + c];
    _Float16 hh = (_Float16)v;
    th[idx] = hh;
    tl[idx] = (_Float16)(v - (float)hh);
}

// ---------------- MFMA GEMM (fp16 2-pass, 2-phase dbuf), plain C epilogue ----------------
// hpre written HEAD-MAJOR fp16: Cc[h][Mpad][64]. XCD panel-affinity 1-D grid.
__global__ __launch_bounds__(256) void k_gemm_mfma(const _Float16* __restrict__ A,
                                                   const _Float16* __restrict__ Bh,
                                                   const _Float16* __restrict__ Bl,
                                                   _Float16* __restrict__ Cc, int M, int K, int Pb, int Mpad) {
    __shared__ _Float16 lA[8192], lBh[8192], lBl[8192];   // 2 buffers x 4096
    int bid = blockIdx.x;
    int panel = ((bid >> 5) << 3) + (bid & 7);
    int colb  = (bid >> 3) & 3;
    if (panel >= Pb) return;
    int tid = threadIdx.x;
    int w = tid >> 6, lane = tid & 63;
    int wr = w >> 1, wc = w & 1;
    int r0 = panel * 128, c0 = colb * 128;
    f32x4 acc[4][4] = {};
    int frag_off = ((lane >> 4) * 16 + (lane & 15)) * 8;

    int rb0 = tid >> 6, kc0 = (tid >> 4) & 3, r16_0 = tid & 15;
    int rb1 = (256 + tid) >> 6, kc1 = ((256 + tid) >> 4) & 3;
    long gaBase0 = (long)(r0 + rb0 * 16 + r16_0) * K + kc0 * 8;
    long gbBase0 = (long)(c0 + rb0 * 16 + r16_0) * K + kc0 * 8;
    long gaBase1 = (long)(r0 + rb1 * 16 + r16_0) * K + kc1 * 8;
    long gbBase1 = (long)(c0 + rb1 * 16 + r16_0) * K + kc1 * 8;
    int ldst0 = (w * 64) * 8;
    int ldst1 = (256 + w * 64) * 8;

#define STAGE(buf, k0)  do { \
        int off = (buf) * 4096; \
        GLOAD_LDS16(A  + gaBase0 + (k0), lA  + off + ldst0); \
        GLOAD_LDS16(Bh + gbBase0 + (k0), lBh + off + ldst0); \
        GLOAD_LDS16(Bl + gbBase0 + (k0), lBl + off + ldst0); \
        GLOAD_LDS16(A  + gaBase1 + (k0), lA  + off + ldst1); \
        GLOAD_LDS16(Bh + gbBase1 + (k0), lBh + off + ldst1); \
        GLOAD_LDS16(Bl + gbBase1 + (k0), lBl + off + ldst1); \
    } while (0)

    int nk = K >> 5;
    STAGE(0, 0);
    __syncthreads();
    int cur = 0;
    for (int t = 0; t < nk; ++t) {
        if (t + 1 < nk) STAGE(cur ^ 1, (t + 1) * 32);
        int off = cur * 4096;
        half8v fa[4], fbh[4], fbl[4];
        #pragma unroll
        for (int m = 0; m < 4; ++m) {
            int sa = off + (wr * 4 + m) * 512 + frag_off;
            fa[m] = *reinterpret_cast<half8v*>(&lA[sa]);
            int sb = off + (wc * 4 + m) * 512 + frag_off;
            fbh[m] = *reinterpret_cast<half8v*>(&lBh[sb]);
            fbl[m] = *reinterpret_cast<half8v*>(&lBl[sb]);
        }
        #pragma unroll
        for (int m = 0; m < 4; ++m)
            #pragma unroll
            for (int n = 0; n < 4; ++n) {
                acc[m][n] = __builtin_amdgcn_mfma_f32_16x16x32_f16(fa[m], fbh[n], acc[m][n], 0, 0, 0);
                acc[m][n] = __builtin_amdgcn_mfma_f32_16x16x32_f16(fa[m], fbl[n], acc[m][n], 0, 0, 0);
            }
        __syncthreads();
        cur ^= 1;
    }
#undef STAGE

    int head = colb * 2 + wc;
    long hbase = (long)head * Mpad * 64;
    #pragma unroll
    for (int m = 0; m < 4; ++m)
        #pragma unroll
        for (int j = 0; j < 4; ++j) {
            int gr = r0 + wr * 64 + m * 16 + (lane >> 4) * 4 + j;
            if (gr < M) {
                #pragma unroll
                for (int n = 0; n < 4; ++n)
                    Cc[hbase + (long)gr * 64 + n * 16 + (lane & 15)] = (_Float16)acc[m][n][j];
            }
        }
}

// ---------------- k_edot: attention dots from head-major hpre (coalesced) ----------------
// block = 8 nodes x 8 heads; wave = head; lane = n8*8+cg; half8 reads, 3-shfl reduce.
__global__ __launch_bounds__(512) void k_edot(const half8v* __restrict__ hp8,
                                              const float* __restrict__ a_src,
                                              const float* __restrict__ a_dst,
                                              float* __restrict__ e_src, float* __restrict__ e_dst,
                                              int N, int Mpad) {
    int h = threadIdx.x >> 6, lane = threadIdx.x & 63;
    int n8 = lane >> 3, cg = lane & 7;
    int n = blockIdx.x * 8 + n8;
    bool valid = (n < N);
    int nc = valid ? n : (N - 1);
    float as[8], ad[8];
    #pragma unroll
    for (int k = 0; k < 8; ++k) {
        as[k] = a_src[h * 64 + cg * 8 + k];
        ad[k] = a_dst[h * 64 + cg * 8 + k];
    }
    half8v hv = hp8[(long)h * Mpad * 8 + (long)nc * 8 + cg];
    float es = 0.f, ed = 0.f;
    #pragma unroll
    for (int k = 0; k < 8; ++k) {
        es = fmaf((float)hv[k], as[k], es);
        ed = fmaf((float)hv[k], ad[k], ed);
    }
    #pragma unroll
    for (int o = 1; o <= 4; o <<= 1) {
        es += __shfl_xor(es, o);
        ed += __shfl_xor(ed, o);
    }
    if (valid && cg == 0) {
        e_src[n * 8 + h] = es;
        e_dst[n * 8 + h] = ed;
    }
}

// ---------------- k_edge: single pass — raw p to alp_csr + inv per (node,head) ----------------
// wave = 2 nodes x 4 edge-slots x 8 heads; lane = g*32 + eg*8 + h.
__global__ __launch_bounds__(512) void k_edge(const float* __restrict__ e_src,
                                              const float* __restrict__ e_dst,
                                              const int* __restrict__ row_start,
                                              const int* __restrict__ csr_src,
                                              float* __restrict__ alp_csr,
                                              float* __restrict__ inv_buf,
                                              int N) {
    int wid = threadIdx.x >> 6, lane = threadIdx.x & 63;
    int g = lane >> 5;
    int eg = (lane >> 3) & 3;
    int h = lane & 7;
    int n = blockIdx.x * 16 + wid * 2 + g;
    bool valid = (n < N);
    int nc = valid ? n : (N - 1);
    int row = row_start[nc];
    int deg = row_start[nc + 1] - row;
    float ed = e_dst[nc * 8 + h];
    int it = (deg + 3) >> 2;
    int itmax = max(it, __shfl_xor(it, 32));
    float psum = 0.f;
    for (int c = 0; c < itmax; ++c) {
        int e0 = c * 4 + eg;
        int idx = row + min(e0, deg - 1);
        int s = csr_src[idx];
        float p = (e0 < deg) ? __expf(leaky(e_src[s * 8 + h] + ed)) : 0.f;
        psum += p;
        if (valid && e0 < deg)
            alp_csr[(long)idx * 8 + h] = p;        // raw p, sequential 32B per group
    }
    psum += __shfl_xor(psum, 8);
    psum += __shfl_xor(psum, 16);
    float inv = 1.0f / psum;
    if (valid && eg == 0) inv_buf[n * 8 + h] = inv;
}

// ---------------- k_alpha: CSR-parallel alpha output (p * inv, permuted to eid) ----------------
__global__ void k_alpha(const int* __restrict__ csr_dst, const int* __restrict__ csr_eid,
                        const float* __restrict__ alp_csr, const float* __restrict__ inv_buf,
                        float* __restrict__ alpha, int Et) {
    int idx = blockIdx.x * blockDim.x + threadIdx.x;
    if (idx >= Et) return;
    int d = csr_dst[idx], eid = csr_eid[idx];
    const float4* p4 = reinterpret_cast<const float4*>(alp_csr) + (long)idx * 2;
    const float4* i4 = reinterpret_cast<const float4*>(inv_buf) + (long)d * 2;
    float4 p0 = p4[0], p1 = p4[1], i0 = i4[0], i1 = i4[1];
    float4 r0, r1;
    r0.x = p0.x * i0.x; r0.y = p0.y * i0.y; r0.z = p0.z * i0.z; r0.w = p0.w * i0.w;
    r1.x = p1.x * i1.x; r1.y = p1.y * i1.y; r1.z = p1.z * i1.z; r1.w = p1.w * i1.w;
    float4* o4 = reinterpret_cast<float4*>(alpha) + (long)eid * 2;
    o4[0] = r0;
    o4[1] = r1;
}

// ---------------- k_gather: XCD-affine aggregation, 2-edge unrolled, raw p + inv ----------------
// head = blockIdx.x & 7 (XCD round-robin keeps 2.57MB head slice L2-resident).
// lane = g*32 + eg*8 + cg; per iter each group handles edges {c*8+eg, c*8+4+eg}.
__global__ __launch_bounds__(512) void k_gather(const half8v* __restrict__ hp8,
                                                const int* __restrict__ row_start,
                                                const int* __restrict__ csr_src,
                                                const float* __restrict__ alp_csr,
                                                const float* __restrict__ inv_buf,
                                                const float* __restrict__ bias,
                                                _Float16* __restrict__ h1,
                                                _Float16* __restrict__ accq,
                                                int N, int Mpad, int concat) {
    int wid = threadIdx.x >> 6, lane = threadIdx.x & 63;
    int bid = blockIdx.x;
    int h = bid & 7;
    int g = lane >> 5;
    int eg = (lane >> 3) & 3;
    int cg = lane & 7;
    int n = (bid >> 3) * 16 + wid * 2 + g;
    bool valid = (n < N);
    int nc = valid ? n : (N - 1);
    long hoff = (long)h * Mpad * 8;
    int row = row_start[nc];
    int deg = row_start[nc + 1] - row;
    float inv = inv_buf[nc * 8 + h];
    int it = (deg + 7) >> 3;
    int itmax = max(it, __shfl_xor(it, 32));
    float acc[8] = {};
    // prefetch iter 0 (two slots)
    int idxA = row + min(eg, deg - 1);
    int idxB = row + min(4 + eg, deg - 1);
    int   sA = csr_src[idxA];
    float aA = alp_csr[(long)idxA * 8 + h];
    int   sB = csr_src[idxB];
    float aB = alp_csr[(long)idxB * 8 + h];
    for (int c = 0; c < itmax; ++c) {
        int e0 = c * 8 + eg, e1 = e0 + 4;
        int sA_c = sA, sB_c = sB;
        float aA_c = (e0 < deg) ? aA : 0.f;
        float aB_c = (e1 < deg) ? aB : 0.f;
        if (c + 1 < itmax) {                       // prefetch next pair (index-independent)
            int nA = row + min(e0 + 8, deg - 1);
            int nB = row + min(e1 + 8, deg - 1);
            sA = csr_src[nA];
            aA = alp_csr[(long)nA * 8 + h];
            sB = csr_src[nB];
            aB = alp_csr[(long)nB * 8 + h];
        }
        half8v hA = hp8[hoff + (long)sA_c * 8 + cg];
        half8v hB = hp8[hoff + (long)sB_c * 8 + cg];
        #pragma unroll
        for (int k = 0; k < 8; ++k) {
            acc[k] = fmaf((float)hA[k], aA_c, acc[k]);
            acc[k] = fmaf((float)hB[k], aB_c, acc[k]);
        }
    }
    #pragma unroll
    for (int o = 8; o <= 16; o <<= 1)
        #pragma unroll
        for (int k = 0; k < 8; ++k)
            acc[k] += __shfl_xor(acc[k], o);
    if (!valid) return;
    if (eg == 0) {                     // 8 lanes per node hold the 64 channels
        if (concat) {
            half8v hh;
            #pragma unroll
            for (int k = 0; k < 8; ++k) {
                float v = fmaf(acc[k], inv, bias[h * 64 + cg * 8 + k]);
                v = v > 0.f ? v : 0.f;
                hh[k] = (_Float16)v;
            }
            reinterpret_cast<half8v*>(h1)[(long)n * 64 + h * 8 + cg] = hh;   // node-major
        } else {
            half8v hv2;
            #pragma unroll
            for (int k = 0; k < 8; ++k) hv2[k] = (_Float16)(acc[k] * inv);
            reinterpret_cast<half8v*>(accq)[hoff + (long)n * 8 + cg] = hv2;  // head-major
        }
    }
}

// ---------------- mean over heads + bias (layer 2 finish) ----------------
__global__ void k_mean(const _Float16* __restrict__ accq, const float* __restrict__ bias,
                       float* __restrict__ out, int N, int Mpad) {
    int i = blockIdx.x * blockDim.x + threadIdx.x;   // over N*8 chan-octs
    if (i >= N * 8) return;
    int n = i >> 3, cg = i & 7;
    float s[8] = {};
    #pragma unroll
    for (int h = 0; h < 8; ++h) {
        half8v v = reinterpret_cast<const half8v*>(accq)[(long)h * Mpad * 8 + (long)n * 8 + cg];
        #pragma unroll
        for (int k = 0; k < 8; ++k) s[k] += (float)v[k];
    }
    float4 r0, r1;
    r0.x = s[0] * 0.125f + bias[cg * 8 + 0];
    r0.y = s[1] * 0.125f + bias[cg * 8 + 1];
    r0.z = s[2] * 0.125f + bias[cg * 8 + 2];
    r0.w = s[3] * 0.125f + bias[cg * 8 + 3];
    r1.x = s[4] * 0.125f + bias[cg * 8 + 4];
    r1.y = s[5] * 0.125f + bias[cg * 8 + 5];
    r1.z = s[6] * 0.125f + bias[cg * 8 + 6];
    r1.w = s[7] * 0.125f + bias[cg * 8 + 7];
    float4* o4 = reinterpret_cast<float4*>(out + (long)n * 64 + cg * 8);
    o4[0] = r0;
    o4[1] = r1;
}

extern "C" void kernel_launch(void* const* d_in, const int* in_sizes, int n_in,
                              void* d_out, int out_size, void* d_ws, size_t ws_size,
                              hipStream_t stream) {
    const float* x   = (const float*)d_in[0];
    const int*   ei  = (const int*)d_in[1];
    const float* W1  = (const float*)d_in[2];
    const float* as1 = (const float*)d_in[3];
    const float* ad1 = (const float*)d_in[4];
    const float* b1  = (const float*)d_in[5];
    const float* W2  = (const float*)d_in[6];
    const float* as2 = (const float*)d_in[7];
    const float* ad2 = (const float*)d_in[8];
    const float* b2  = (const float*)d_in[9];

    int N  = in_sizes[0] / 256;
    int E  = in_sizes[1] / 2;
    int Et = E + N;
    int K1 = 256;
    int Mb   = (N + 127) / 128;
    int Mpad = Mb * 128;

    float* out    = (float*)d_out;
    float* h2_out = out;
    float* alpha1 = out + (size_t)N * 64;
    float* alpha2 = alpha1 + (size_t)Et * H;

    _Float16* hpre = (_Float16*)d_ws;                      // [8][Mpad][64] head-major
    _Float16* h1   = hpre + (size_t)Mpad * HC;             // [Mpad][512] node-major
    _Float16* accq = h1 + (size_t)Mpad * HC;               // [8][Mpad][64] head-major
    _Float16* xh   = accq + (size_t)Mpad * HC;             // [Mpad][256]
    _Float16* W1th = xh + (size_t)Mpad * K1;               // [512][256]
    _Float16* W1tl = W1th + (size_t)HC * K1;
    _Float16* W2th = W1tl + (size_t)HC * K1;               // [512][512]
    _Float16* W2tl = W2th + (size_t)HC * HC;
    float* eS     = (float*)(W2tl + (size_t)HC * HC);      // [N][8]
    float* eD     = eS + (size_t)N * H;
    float* alpcsr = eD + (size_t)N * H;                    // [Et][8]
    float* invb   = alpcsr + (size_t)Et * H;               // [N][8]
    int*   deg    = (int*)(invb + (size_t)N * H);
    int*   cursor = deg + N;
    int*   row_st = cursor + N;
    int*   csr_src= row_st + N + 1;                        // Et
    int*   csr_eid= csr_src + Et;                          // Et
    int*   csr_dst= csr_eid + Et;                          // Et

    hipMemsetAsync(deg, 0, (size_t)2 * N * sizeof(int), stream);
    int tb = 256;
    k_degree<<<(Et + tb - 1) / tb, tb, 0, stream>>>(ei, E, N, deg);
    k_scan<<<1, 1024, 0, stream>>>(deg, N, row_st);
    k_fill<<<(Et + tb - 1) / tb, tb, 0, stream>>>(ei, E, N, row_st, cursor, csr_src, csr_eid, csr_dst);

    int n4 = N * K1 / 4;
    k_tofp16<<<(n4 + tb - 1) / tb, tb, 0, stream>>>(x, xh, n4);
    k_tsplit<<<(K1 * HC + tb - 1) / tb, tb, 0, stream>>>(W1, W1th, W1tl, K1, HC);
    k_tsplit<<<(HC * HC + tb - 1) / tb, tb, 0, stream>>>(W2, W2th, W2tl, HC, HC);

    int Pb8 = ((Mb + 7) / 8) * 8;
    int ggemm = Pb8 * 4;
    int gedot = (N + 7) / 8;
    int gedge = (N + 15) / 16;
    int ggath = ((N + 15) / 16) * 8;   // low 3 bits = head (XCD affinity)
    // layer 1
    k_gemm_mfma<<<ggemm, 256, 0, stream>>>(xh, W1th, W1tl, hpre, N, K1, Mb, Mpad);
    k_edot<<<gedot, 512, 0, stream>>>((const half8v*)hpre, as1, ad1, eS, eD, N, Mpad);
    k_edge<<<gedge, 512, 0, stream>>>(eS, eD, row_st, csr_src, alpcsr, invb, N);
    k_alpha<<<(Et + tb - 1) / tb, tb, 0, stream>>>(csr_dst, csr_eid, alpcsr, invb, alpha1, Et);
    k_gather<<<ggath, 512, 0, stream>>>((const half8v*)hpre, row_st, csr_src, alpcsr, invb,
                                        b1, h1, nullptr, N, Mpad, 1);
    // layer 2
    k_gemm_mfma<<<ggemm, 256, 0, stream>>>(h1, W2th, W2tl, hpre, N, HC, Mb, Mpad);
    k_edot<<<gedot, 512, 0, stream>>>((const half8v*)hpre, as2, ad2, eS, eD, N, Mpad);
    k_edge<<<gedge, 512, 0, stream>>>(eS, eD, row_st, csr_src, alpcsr, invb, N);
    k_alpha<<<(Et + tb - 1) / tb, tb, 0, stream>>>(csr_dst, csr_eid, alpcsr, invb, alpha2, Et);
    k_gather<<<ggath, 512, 0, stream>>>((const half8v*)hpre, row_st, csr_src, alpcsr, invb,
                                        b2, nullptr, accq, N, Mpad, 0);
    k_mean<<<(N * 8 + tb - 1) / tb, tb, 0, stream>>>(accq, b2, h2_out, N, Mpad);
}